// Round 1
// baseline (2085.390 us; speedup 1.0000x reference)
//
#include <hip/hip_runtime.h>
#include <math.h>

#define NB 2048
#define NT 64
#define DD 1024
#define HH 512
#define KTOP 15
#define KC 16
#define NCHUNK (DD / KC)

// ---------------------------------------------------------------------------
// Prep: c1[j] = sum_d gamma[d]*w1[d,j];  c2b[j] = sum_d beta[d]*w1[d,j] + b1[j]
// (LayerNorm folded into the GEMM epilogue: h_pre = r*acc - r*mu*c1 + c2b)
// ---------------------------------------------------------------------------
__global__ void prep_kernel(const float* __restrict__ w1,
                            const float* __restrict__ gamma,
                            const float* __restrict__ beta,
                            const float* __restrict__ b1,
                            float* __restrict__ c1g,
                            float* __restrict__ c2g) {
  const int j = blockIdx.x * 256 + threadIdx.x;  // grid=2 -> j in [0,512)
  float a = 0.f, c = 0.f;
  for (int d = 0; d < DD; ++d) {
    float w = w1[d * HH + j];
    a = fmaf(gamma[d], w, a);
    c = fmaf(beta[d], w, c);
  }
  c1g[j] = a;
  c2g[j] = c + b1[j];
}

// ---------------------------------------------------------------------------
// Fused: per block = one batch row b.
//   - VALU fp32 GEMM: 64 tokens x 512 hidden, K=1024 in chunks of 16
//   - per-token mean/rsqrt computed from staged A tiles
//   - relu + w2 dot -> scores; wave-0 top-15 (jax tie-break: lower idx first)
//   - gather topk tokens + background mean via (colsum - selsum)/49
// ---------------------------------------------------------------------------
__global__ __launch_bounds__(256, 2) void score_gather_kernel(
    const float* __restrict__ tokens,
    const float* __restrict__ w1,
    const float* __restrict__ w2,
    const float* __restrict__ gamma,
    const float* __restrict__ c1g,
    const float* __restrict__ c2g,
    float* __restrict__ out) {
  __shared__ float Asm[KC][NT];      // 4 KiB   A tile [k][token] (transposed)
  __shared__ float Bsm[KC][HH];      // 32 KiB  B tile [k][hidden], gamma-scaled
  __shared__ float colsum[DD];       // 4 KiB   sum over tokens per d (for bg)
  __shared__ float gam[DD];          // 4 KiB
  __shared__ float s1p[4][NT];       // 1 KiB   token-sum partials
  __shared__ float s2p[4][NT];       // 1 KiB   token-sumsq partials
  __shared__ float r_s[NT];
  __shared__ float rmu_s[NT];
  __shared__ float scp[32][NT];      // 8 KiB   score partials [hgroup][token]
  __shared__ int   topk_s[KTOP];

  const int tid = threadIdx.x;
  const int b   = blockIdx.x;
  const int tg  = tid & 7;    // token group: tokens 8*tg .. 8*tg+7
  const int hg  = tid >> 3;   // hidden group: cols 128*di + 4*hg + q

  // preload gamma, zero colsum (visible after first barrier)
  {
    float4 g = *(const float4*)(gamma + tid * 4);
    *(float4*)(&gam[tid * 4]) = g;
    float4 z = {0.f, 0.f, 0.f, 0.f};
    *(float4*)(&colsum[tid * 4]) = z;
  }

  float acc[8][16];
#pragma unroll
  for (int i = 0; i < 8; ++i)
#pragma unroll
    for (int u = 0; u < 16; ++u) acc[i][u] = 0.f;

  float s1r = 0.f, s2r = 0.f;

  // staging mappings
  const int at = tid >> 2, aq = tid & 3;        // A: token at, k-quad aq
  const int bk = (tid >> 7) * 8;                // B: k rows bk..bk+7
  const int bj = (tid & 127) * 4;               // B: 4 cols at bj
  const float* tokp = tokens + (size_t)b * NT * DD + at * DD + aq * 4;
  const float* w1p  = w1 + bk * HH + bj;

  // prefetch chunk 0 into registers
  float4 pA = *(const float4*)(tokp);
  float4 pB[8];
#pragma unroll
  for (int u = 0; u < 8; ++u) pB[u] = *(const float4*)(w1p + u * HH);

  for (int c = 0; c < NCHUNK; ++c) {
    const int k0 = c * KC;
    __syncthreads();  // previous chunk's LDS reads done
    // regs -> LDS (A transposed; B scaled by gamma)
    Asm[aq * 4 + 0][at] = pA.x;
    Asm[aq * 4 + 1][at] = pA.y;
    Asm[aq * 4 + 2][at] = pA.z;
    Asm[aq * 4 + 3][at] = pA.w;
#pragma unroll
    for (int u = 0; u < 8; ++u) {
      float g = gam[k0 + bk + u];
      float4 v = pB[u];
      v.x *= g; v.y *= g; v.z *= g; v.w *= g;
      *(float4*)(&Bsm[bk + u][bj]) = v;
    }
    __syncthreads();
    // issue next chunk's global loads (latency hidden under FMAs)
    if (c + 1 < NCHUNK) {
      tokp += KC;
      w1p += KC * HH;
      pA = *(const float4*)(tokp);
#pragma unroll
      for (int u = 0; u < 8; ++u) pB[u] = *(const float4*)(w1p + u * HH);
    }
    // per-token stats partials (wave w handles k rows 4w..4w+3)
    {
      const int t = tid & 63, kq = tid >> 6;
#pragma unroll
      for (int q = 0; q < 4; ++q) {
        float v = Asm[kq * 4 + q][t];
        s1r += v;
        s2r = fmaf(v, v, s2r);
      }
    }
    // column sums over tokens (for background mean)
    {
      const int kk = tid >> 4, tq = tid & 15;
      float v = 0.f;
#pragma unroll
      for (int q = 0; q < 4; ++q) v += Asm[kk][tq * 4 + q];
      v += __shfl_down(v, 8, 16);
      v += __shfl_down(v, 4, 16);
      v += __shfl_down(v, 2, 16);
      v += __shfl_down(v, 1, 16);
      if (tq == 0) colsum[k0 + kk] += v;
    }
    // 8x16 register-tile FMA over this K chunk
#pragma unroll 4
    for (int k = 0; k < KC; ++k) {
      float4 A0 = *(const float4*)(&Asm[k][tg * 8]);
      float4 A1 = *(const float4*)(&Asm[k][tg * 8 + 4]);
      float4 B0 = *(const float4*)(&Bsm[k][hg * 4]);
      float4 B1 = *(const float4*)(&Bsm[k][128 + hg * 4]);
      float4 B2 = *(const float4*)(&Bsm[k][256 + hg * 4]);
      float4 B3 = *(const float4*)(&Bsm[k][384 + hg * 4]);
      const float av[8] = {A0.x, A0.y, A0.z, A0.w, A1.x, A1.y, A1.z, A1.w};
      const float bv[16] = {B0.x, B0.y, B0.z, B0.w, B1.x, B1.y, B1.z, B1.w,
                            B2.x, B2.y, B2.z, B2.w, B3.x, B3.y, B3.z, B3.w};
#pragma unroll
      for (int i = 0; i < 8; ++i)
#pragma unroll
        for (int u = 0; u < 16; ++u)
          acc[i][u] = fmaf(av[i], bv[u], acc[i][u]);
    }
  }

  // finalize per-token mean / rsqrt
  {
    const int t = tid & 63, kq = tid >> 6;
    s1p[kq][t] = s1r;
    s2p[kq][t] = s2r;
  }
  __syncthreads();
  if (tid < NT) {
    float s1 = s1p[0][tid] + s1p[1][tid] + s1p[2][tid] + s1p[3][tid];
    float s2 = s2p[0][tid] + s2p[1][tid] + s2p[2][tid] + s2p[3][tid];
    float mu = s1 * (1.0f / DD);
    float var = s2 * (1.0f / DD) - mu * mu;
    float r = 1.0f / sqrtf(var + 1e-5f);
    r_s[tid] = r;
    rmu_s[tid] = r * mu;
  }
  __syncthreads();

  // epilogue: h = relu(r*acc - r*mu*c1 + c2b); score partial = h . w2
  {
    float4 C1[4], C2[4], W2[4];
#pragma unroll
    for (int d = 0; d < 4; ++d) {
      C1[d] = *(const float4*)(c1g + d * 128 + hg * 4);
      C2[d] = *(const float4*)(c2g + d * 128 + hg * 4);
      W2[d] = *(const float4*)(w2 + d * 128 + hg * 4);
    }
    const float c1v[16] = {C1[0].x, C1[0].y, C1[0].z, C1[0].w,
                           C1[1].x, C1[1].y, C1[1].z, C1[1].w,
                           C1[2].x, C1[2].y, C1[2].z, C1[2].w,
                           C1[3].x, C1[3].y, C1[3].z, C1[3].w};
    const float c2v[16] = {C2[0].x, C2[0].y, C2[0].z, C2[0].w,
                           C2[1].x, C2[1].y, C2[1].z, C2[1].w,
                           C2[2].x, C2[2].y, C2[2].z, C2[2].w,
                           C2[3].x, C2[3].y, C2[3].z, C2[3].w};
    const float w2v[16] = {W2[0].x, W2[0].y, W2[0].z, W2[0].w,
                           W2[1].x, W2[1].y, W2[1].z, W2[1].w,
                           W2[2].x, W2[2].y, W2[2].z, W2[2].w,
                           W2[3].x, W2[3].y, W2[3].z, W2[3].w};
#pragma unroll
    for (int i = 0; i < 8; ++i) {
      int t = tg * 8 + i;
      float r = r_s[t], rm = rmu_s[t];
      float sp = 0.f;
#pragma unroll
      for (int u = 0; u < 16; ++u) {
        float h = fmaf(r, acc[i][u], fmaf(-rm, c1v[u], c2v[u]));
        h = fmaxf(h, 0.f);
        sp = fmaf(h, w2v[u], sp);
      }
      scp[hg][t] = sp;
    }
  }
  __syncthreads();

  // wave-0 top-15: butterfly argmax, ties -> lower index (jax top_k semantics)
  if (tid < NT) {
    float s = 0.f;
#pragma unroll
    for (int h = 0; h < 32; ++h) s += scp[h][tid];
    int idx = tid;
    for (int it = 0; it < KTOP; ++it) {
      float bs = s;
      int bi = idx;
#pragma unroll
      for (int off = 32; off > 0; off >>= 1) {
        float os = __shfl_xor(bs, off);
        int oi = __shfl_xor(bi, off);
        if (os > bs || (os == bs && oi < bi)) { bs = os; bi = oi; }
      }
      if (tid == 0) topk_s[it] = bi;
      if (idx == bi) s = -INFINITY;
    }
  }
  __syncthreads();

  // output: row 0 = background mean, rows 1..15 = gathered top-k tokens
  {
    const float* tb = tokens + (size_t)b * NT * DD;
    float* ob = out + (size_t)b * 16 * DD;
    float4 sel = {0.f, 0.f, 0.f, 0.f};
#pragma unroll
    for (int sI = 0; sI < KTOP; ++sI) {
      int t = topk_s[sI];
      float4 v = *(const float4*)(tb + t * DD + tid * 4);
      *(float4*)(ob + (1 + sI) * DD + tid * 4) = v;
      sel.x += v.x; sel.y += v.y; sel.z += v.z; sel.w += v.w;
    }
    float4 cs = *(const float4*)(&colsum[tid * 4]);
    const float inv = 1.0f / 49.0f;  // bg_count = 64 - 15
    float4 bg;
    bg.x = (cs.x - sel.x) * inv;
    bg.y = (cs.y - sel.y) * inv;
    bg.z = (cs.z - sel.z) * inv;
    bg.w = (cs.w - sel.w) * inv;
    *(float4*)(ob + tid * 4) = bg;
  }
}

extern "C" void kernel_launch(void* const* d_in, const int* in_sizes, int n_in,
                              void* d_out, int out_size, void* d_ws, size_t ws_size,
                              hipStream_t stream) {
  const float* tokens = (const float*)d_in[0];
  const float* gamma  = (const float*)d_in[1];
  const float* beta   = (const float*)d_in[2];
  const float* w1     = (const float*)d_in[3];
  const float* b1     = (const float*)d_in[4];
  const float* w2     = (const float*)d_in[5];
  // d_in[6] = b2: constant shift, cannot change top-k selection/order and
  // scores are not part of the output -> intentionally unused.
  float* out = (float*)d_out;
  float* c1g = (float*)d_ws;       // 512 floats
  float* c2g = c1g + HH;           // 512 floats

  prep_kernel<<<2, 256, 0, stream>>>(w1, gamma, beta, b1, c1g, c2g);
  score_gather_kernel<<<NB, 256, 0, stream>>>(tokens, w1, w2, gamma, c1g, c2g, out);
}